// Round 5
// baseline (69.240 us; speedup 1.0000x reference)
//
#include <hip/hip_runtime.h>

// ---- problem constants ----
#define HOP 160
#define NROWS 402            // 2*CUT
#define NTAPS 400            // N_FFT
#define T_SIG 9600000
#define N_FRAMES 60001
#define PAD 200              // CUT-1

// ---- tiling ----
#define MT 13                // 13 m-tiles * 32 rows = 416 (rows padded)
#define KS 26                // 26 k-steps * 16 taps = 416 (taps padded)
#define FPB 128              // frames per block (4 subtiles of 32)
#define MGROUPS 4            // m-tile groups (4 waves each -> 16 slots, 13 real)
#define NBT ((N_FRAMES + FPB - 1) / FPB)  // 469 frame-blocks
#define SPAN (127*HOP + 416) // 20736 signal floats staged per block
#define SPAN4 (SPAN/4)
#define LDSE 21776           // padded bf16 elems: 20736 + 8 per 160 block

typedef __bf16 bf16x8 __attribute__((ext_vector_type(8)));
typedef float f32x16 __attribute__((ext_vector_type(16)));
typedef unsigned short u16x8 __attribute__((ext_vector_type(8)));
typedef unsigned short u16x4 __attribute__((ext_vector_type(4)));

__device__ __forceinline__ unsigned short f2bf(float f) {
    // round-to-nearest-even fp32 -> bf16 (inputs are finite)
    unsigned int u = __builtin_bit_cast(unsigned int, f);
    u += 0x7fffu + ((u >> 16) & 1u);
    return (unsigned short)(u >> 16);
}

// Pack basis fp32[402][400] -> bf16 in per-fragment lane order:
// packed[((mt*KS+ks)*64 + lane)*8 + i] = bf16(basis[mt*32+(lane&31)][ks*16+8*(lane>>5)+i])
__global__ void stft_prep(const float* __restrict__ basis,
                          unsigned short* __restrict__ packed) {
    int tid = blockIdx.x * 256 + threadIdx.x;
    if (tid >= MT * KS * 64) return;
    int lane = tid & 63;
    int frag = tid >> 6;
    int ks = frag % KS;
    int mt = frag / KS;
    int row = mt * 32 + (lane & 31);
    int colb = ks * 16 + (lane >> 5) * 8;
    u16x8 v;
#pragma unroll
    for (int i = 0; i < 8; ++i) {
        int col = colb + i;
        float f = (row < NROWS && col < NTAPS) ? basis[row * NTAPS + col] : 0.0f;
        v[i] = f2bf(f);
    }
    *reinterpret_cast<u16x8*>(packed + (size_t)tid * 8) = v;
}

// C[row][t] = sum_c basis[row][c] * sig[t*160 + c - 200]
// Weight-stationary: grid = NBT x MGROUPS (m-group fastest -> same-bt blocks
// dispatch together, signal span L2/L3-shared). Each wave owns ONE m-tile:
// A-frags loaded ONCE into 104 VGPRs (issued before staging so latency hides
// under it), then 4 frame-subtiles of pure {ds_read_b128 + MFMA}. No global
// loads and no barriers in the compute loop.
__launch_bounds__(256, 3)
__global__ void stft_mfma(const float* __restrict__ sig,
                          const unsigned short* __restrict__ packedA,
                          float* __restrict__ out) {
    // bf16 signal tile, +8 elems per 160 -> measured conflicts negligible
    __shared__ unsigned short sl[LDSE];
    const int tid = threadIdx.x;
    const int bg = blockIdx.x & (MGROUPS - 1);   // m-group
    const int bt = blockIdx.x >> 2;              // frame-block
    const int lane = tid & 63;
    const int w = tid >> 6;
    const int mt = bg * 4 + w;                   // wave's m-tile, real if < 13

    // Issue the wave's 26 A-frag loads FIRST; they complete under staging.
    bf16x8 afr[KS];
    if (mt < MT) {
        const unsigned short* pA = packedA + ((size_t)(mt * KS) * 64 + lane) * 8;
#pragma unroll
        for (int ks = 0; ks < KS; ++ks)
            afr[ks] = *reinterpret_cast<const bf16x8*>(pA + (size_t)ks * 512);
    }

    // stage signal span -> bf16 LDS (coalesced float4, edge-guarded)
    const long sbase = (long)bt * (FPB * HOP) - PAD;
    for (int idx = tid; idx < SPAN4; idx += 256) {
        const int e = idx * 4;
        const long g0 = sbase + e;
        float4 v;
        if (g0 >= 0 && g0 + 4 <= (long)T_SIG) {
            v = *reinterpret_cast<const float4*>(sig + g0);
        } else {
            v.x = (g0 + 0 >= 0 && g0 + 0 < (long)T_SIG) ? sig[g0 + 0] : 0.0f;
            v.y = (g0 + 1 >= 0 && g0 + 1 < (long)T_SIG) ? sig[g0 + 1] : 0.0f;
            v.z = (g0 + 2 >= 0 && g0 + 2 < (long)T_SIG) ? sig[g0 + 2] : 0.0f;
            v.w = (g0 + 3 >= 0 && g0 + 3 < (long)T_SIG) ? sig[g0 + 3] : 0.0f;
        }
        u16x4 s;
        s[0] = f2bf(v.x); s[1] = f2bf(v.y); s[2] = f2bf(v.z); s[3] = f2bf(v.w);
        const int pos = e + 8 * (e / 160);  // 4-chunk never crosses a 160 block
        *reinterpret_cast<u16x4*>(&sl[pos]) = s;
    }
    __syncthreads();

    if (mt >= MT) return;  // idle slot waves (13..15) exit after barrier

    const int l31 = lane & 31;
    const int g = lane >> 5;       // k-group
    const int rb = mt * 32 + 4 * g;

#pragma unroll 1
    for (int i = 0; i < FPB / 32; ++i) {
        const int lf = i * 32 + l31;
        const long t = (long)bt * FPB + lf;
        const unsigned short* bb = &sl[lf * 168 + g * 8];
        f32x16 acc = {0,0,0,0,0,0,0,0,0,0,0,0,0,0,0,0};
#pragma unroll
        for (int ks = 0; ks < KS; ++ks) {
            const bf16x8 b = *reinterpret_cast<const bf16x8*>(bb + ks * 16 + 8 * (ks / 10));
            acc = __builtin_amdgcn_mfma_f32_32x32x16_bf16(afr[ks], b, acc, 0, 0, 0);
        }
        if (t < N_FRAMES) {
#pragma unroll
            for (int r = 0; r < 16; ++r) {
                // C/D map: row=(r&3)+8*(r>>2)+4*(lane>>5), col=lane&31
                const int row = rb + (r & 3) + 8 * (r >> 2);
                if (row < NROWS) out[(long)row * N_FRAMES + t] = acc[r];
            }
        }
    }
}

// Correct-but-slow fallback if d_ws can't hold the packed basis (346 KB).
__global__ void stft_naive(const float* __restrict__ sig,
                           const float* __restrict__ basis,
                           float* __restrict__ out) {
    long idx = (long)blockIdx.x * 256 + threadIdx.x;
    if (idx >= (long)NROWS * N_FRAMES) return;
    int row = (int)(idx / N_FRAMES);
    int tt = (int)(idx % N_FRAMES);
    long s0 = (long)tt * HOP - PAD;
    float acc = 0.0f;
    for (int n = 0; n < NTAPS; ++n) {
        long s = s0 + n;
        float x = (s >= 0 && s < (long)T_SIG) ? sig[s] : 0.0f;
        acc = fmaf(x, basis[row * NTAPS + n], acc);
    }
    out[idx] = acc;
}

extern "C" void kernel_launch(void* const* d_in, const int* in_sizes, int n_in,
                              void* d_out, int out_size, void* d_ws, size_t ws_size,
                              hipStream_t stream) {
    (void)in_sizes; (void)n_in; (void)out_size;
    const float* sig = (const float*)d_in[0];
    const float* basis = (const float*)d_in[1];
    float* out = (float*)d_out;
    const size_t need = (size_t)MT * KS * 64 * 8 * sizeof(unsigned short); // 346112 B
    if (ws_size >= need) {
        unsigned short* packed = (unsigned short*)d_ws;
        stft_prep<<<(MT * KS * 64 + 255) / 256, 256, 0, stream>>>(basis, packed);
        stft_mfma<<<NBT * MGROUPS, 256, 0, stream>>>(sig, packed, out);
    } else {
        long total = (long)NROWS * N_FRAMES;
        stft_naive<<<(int)((total + 255) / 256), 256, 0, stream>>>(sig, basis, out);
    }
}

// Round 6
// 68.190 us; speedup vs baseline: 1.0154x; 1.0154x over previous
//
#include <hip/hip_runtime.h>

// ---- problem constants ----
#define HOP 160
#define NROWS 402            // 2*CUT
#define NTAPS 400            // N_FFT
#define T_SIG 9600000
#define N_FRAMES 60001
#define PAD 200              // CUT-1

// ---- tiling ----
#define MT 13                // 13 m-tiles * 32 rows = 416 (rows padded)
#define KS 26                // 26 k-steps * 16 taps = 416 (taps padded)
#define FPB 128              // frames per block (4 subtiles of 32)
#define MGROUPS 4            // m-tile groups (4 waves each -> 16 slots, 13 real)
#define NBT ((N_FRAMES + FPB - 1) / FPB)  // 469 frame-blocks
#define SPAN (127*HOP + 416) // 20736 signal floats staged per block
#define SPAN4 (SPAN/4)
#define LDSE 21776           // padded bf16 elems: 20736 + 8 per 160 block

typedef __bf16 bf16x8 __attribute__((ext_vector_type(8)));
typedef float f32x16 __attribute__((ext_vector_type(16)));
typedef unsigned short u16x8 __attribute__((ext_vector_type(8)));
typedef unsigned short u16x4 __attribute__((ext_vector_type(4)));
typedef unsigned int u32x4 __attribute__((ext_vector_type(4)));

__device__ __forceinline__ unsigned short f2bf(float f) {
    // round-to-nearest-even fp32 -> bf16 (inputs are finite)
    unsigned int u = __builtin_bit_cast(unsigned int, f);
    u += 0x7fffu + ((u >> 16) & 1u);
    return (unsigned short)(u >> 16);
}

// Pack basis fp32[402][400] -> bf16 in per-fragment lane order:
// packed[((mt*KS+ks)*64 + lane)*8 + i] = bf16(basis[mt*32+(lane&31)][ks*16+8*(lane>>5)+i])
__global__ void stft_prep(const float* __restrict__ basis,
                          unsigned short* __restrict__ packed) {
    int tid = blockIdx.x * 256 + threadIdx.x;
    if (tid >= MT * KS * 64) return;
    int lane = tid & 63;
    int frag = tid >> 6;
    int ks = frag % KS;
    int mt = frag / KS;
    int row = mt * 32 + (lane & 31);
    int colb = ks * 16 + (lane >> 5) * 8;
    u16x8 v;
#pragma unroll
    for (int i = 0; i < 8; ++i) {
        int col = colb + i;
        float f = (row < NROWS && col < NTAPS) ? basis[row * NTAPS + col] : 0.0f;
        v[i] = f2bf(f);
    }
    *reinterpret_cast<u16x8*>(packed + (size_t)tid * 8) = v;
}

// C[row][t] = sum_c basis[row][c] * sig[t*160 + c - 200]
// Weight-stationary, REGISTER-PINNED: each wave owns one m-tile whose 26
// A-frags are loaded once and pinned into 104 VGPRs via empty read-write
// inline asm (defeats LLVM's load sinking/remat, which kept VGPR at 68-76
// and MfmaUtil at 10% in R1/R4/R5). Compute loop is pure ds_read+MFMA.
__launch_bounds__(256, 3)
__global__ void stft_mfma(const float* __restrict__ sig,
                          const unsigned short* __restrict__ packedA,
                          float* __restrict__ out) {
    __shared__ unsigned short sl[LDSE];
    const int tid = threadIdx.x;
    const int bg = blockIdx.x & (MGROUPS - 1);   // m-group (fastest -> same-bt blocks adjacent)
    const int bt = blockIdx.x >> 2;              // frame-block
    const int lane = tid & 63;
    const int w = tid >> 6;
    const int mt = bg * 4 + w;                   // wave's m-tile, real if < 13

    // Issue the wave's 26 A-frag loads first; latency hides under staging.
    u32x4 a4[KS];
    if (mt < MT) {
        const unsigned short* pA = packedA + ((size_t)(mt * KS) * 64 + lane) * 8;
#pragma unroll
        for (int ks = 0; ks < KS; ++ks)
            a4[ks] = *reinterpret_cast<const u32x4*>(pA + (size_t)ks * 512);
    }

    // stage signal span -> bf16 LDS (coalesced float4, edge-guarded)
    const long sbase = (long)bt * (FPB * HOP) - PAD;
    for (int idx = tid; idx < SPAN4; idx += 256) {
        const int e = idx * 4;
        const long g0 = sbase + e;
        float4 v;
        if (g0 >= 0 && g0 + 4 <= (long)T_SIG) {
            v = *reinterpret_cast<const float4*>(sig + g0);
        } else {
            v.x = (g0 + 0 >= 0 && g0 + 0 < (long)T_SIG) ? sig[g0 + 0] : 0.0f;
            v.y = (g0 + 1 >= 0 && g0 + 1 < (long)T_SIG) ? sig[g0 + 1] : 0.0f;
            v.z = (g0 + 2 >= 0 && g0 + 2 < (long)T_SIG) ? sig[g0 + 2] : 0.0f;
            v.w = (g0 + 3 >= 0 && g0 + 3 < (long)T_SIG) ? sig[g0 + 3] : 0.0f;
        }
        u16x4 s;
        s[0] = f2bf(v.x); s[1] = f2bf(v.y); s[2] = f2bf(v.z); s[3] = f2bf(v.w);
        const int pos = e + 8 * (e / 160);  // 4-chunk never crosses a 160 block
        *reinterpret_cast<u16x4*>(&sl[pos]) = s;
    }
    __syncthreads();

    if (mt >= MT) return;  // idle slot waves (13..15) exit after the barrier

    // PIN: read-write empty asm makes each frag "asm-defined" -> the compiler
    // can no longer rematerialize it from memory; must stay in VGPRs.
#pragma unroll
    for (int ks = 0; ks < KS; ++ks)
        asm volatile("" : "+v"(a4[ks]));

    const int l31 = lane & 31;
    const int g = lane >> 5;       // k-group
    const int rb = mt * 32 + 4 * g;

#pragma unroll 1
    for (int i = 0; i < FPB / 32; ++i) {
        const int lf = i * 32 + l31;
        const long t = (long)bt * FPB + lf;
        const unsigned short* bb = &sl[lf * 168 + g * 8];
        f32x16 acc = {0,0,0,0,0,0,0,0,0,0,0,0,0,0,0,0};
#pragma unroll
        for (int ks = 0; ks < KS; ++ks) {
            const bf16x8 b = *reinterpret_cast<const bf16x8*>(bb + ks * 16 + 8 * (ks / 10));
            acc = __builtin_amdgcn_mfma_f32_32x32x16_bf16(
                __builtin_bit_cast(bf16x8, a4[ks]), b, acc, 0, 0, 0);
        }
        if (t < N_FRAMES) {
#pragma unroll
            for (int r = 0; r < 16; ++r) {
                // C/D map: row=(r&3)+8*(r>>2)+4*(lane>>5), col=lane&31
                const int row = rb + (r & 3) + 8 * (r >> 2);
                if (row < NROWS) out[(long)row * N_FRAMES + t] = acc[r];
            }
        }
    }
}

// Correct-but-slow fallback if d_ws can't hold the packed basis (346 KB).
__global__ void stft_naive(const float* __restrict__ sig,
                           const float* __restrict__ basis,
                           float* __restrict__ out) {
    long idx = (long)blockIdx.x * 256 + threadIdx.x;
    if (idx >= (long)NROWS * N_FRAMES) return;
    int row = (int)(idx / N_FRAMES);
    int tt = (int)(idx % N_FRAMES);
    long s0 = (long)tt * HOP - PAD;
    float acc = 0.0f;
    for (int n = 0; n < NTAPS; ++n) {
        long s = s0 + n;
        float x = (s >= 0 && s < (long)T_SIG) ? sig[s] : 0.0f;
        acc = fmaf(x, basis[row * NTAPS + n], acc);
    }
    out[idx] = acc;
}

extern "C" void kernel_launch(void* const* d_in, const int* in_sizes, int n_in,
                              void* d_out, int out_size, void* d_ws, size_t ws_size,
                              hipStream_t stream) {
    (void)in_sizes; (void)n_in; (void)out_size;
    const float* sig = (const float*)d_in[0];
    const float* basis = (const float*)d_in[1];
    float* out = (float*)d_out;
    const size_t need = (size_t)MT * KS * 64 * 8 * sizeof(unsigned short); // 346112 B
    if (ws_size >= need) {
        unsigned short* packed = (unsigned short*)d_ws;
        stft_prep<<<(MT * KS * 64 + 255) / 256, 256, 0, stream>>>(basis, packed);
        stft_mfma<<<NBT * MGROUPS, 256, 0, stream>>>(sig, packed, out);
    } else {
        long total = (long)NROWS * N_FRAMES;
        stft_naive<<<(int)((total + 255) / 256), 256, 0, stream>>>(sig, basis, out);
    }
}

// Round 7
// 67.782 us; speedup vs baseline: 1.0215x; 1.0060x over previous
//
#include <hip/hip_runtime.h>

// ---- problem constants ----
#define HOP 160
#define NROWS 402
#define NTAPS 400
#define T_SIG 9600000
#define N_FRAMES 60001
#define PAD 200

typedef __bf16 bf16x8 __attribute__((ext_vector_type(8)));
typedef float f32x16 __attribute__((ext_vector_type(16)));
typedef unsigned short u16x8 __attribute__((ext_vector_type(8)));
typedef unsigned short u16x4 __attribute__((ext_vector_type(4)));
typedef unsigned int u32x4 __attribute__((ext_vector_type(4)));

__device__ __forceinline__ unsigned short f2bf(float f) {
    unsigned int u = __builtin_bit_cast(unsigned int, f);
    u += 0x7fffu + ((u >> 16) & 1u);
    return (unsigned short)(u >> 16);
}

__device__ __forceinline__ void gll16(const void* g, void* l) {
    __builtin_amdgcn_global_load_lds(
        (const __attribute__((address_space(1))) unsigned int*)g,
        (__attribute__((address_space(3))) unsigned int*)l, 16, 0, 0);
}

// ================= TIER 1: GEMM-structured (m97-style) =================
// C[row][t] = sum_k basis[row][k] * sig[t*160 + k - 200]
// sigbf_pad in ws: bf16, shifted +200, +8 elems pad per 160 (bank decorr),
//   so block bt's LDS window = contiguous 43552 B at byte bt*43008.
// Apack in ws: [bm][phase][ksg][r][8] bf16, phases of {7,7,6,6} k16-steps.

#define SIG_OFF 425984            // byte offset of sig region in ws
#define APH0 0
#define APH1 28672
#define APH2 57344
#define APH3 81920
#define ABM_STRIDE 106496         // bytes of Apack per 128-row block
#define A_LDS_B 30720             // A LDS buf: 128 rows * 240 B
#define SIG_LDS_B 45056           // 2816 slots * 16 B
#define NEED1 (425984UL + 20172800UL)

// prep: fp32 signal -> padded bf16 array (covers i in [0, 9605760))
__global__ void prep_sig(const float* __restrict__ sig,
                         unsigned short* __restrict__ sp) {
    long chunk = (long)blockIdx.x * 256 + threadIdx.x;
    if (chunk >= 2401440L) return;
    long i = chunk * 4;
    long pos = i + 8 * (i / 160);   // 4-chunk never crosses a 160-boundary
    u16x4 v;
    if (i >= 200 && i + 4 <= 9600200L) {
        float4 f = *reinterpret_cast<const float4*>(sig + (i - 200));
        v[0] = f2bf(f.x); v[1] = f2bf(f.y); v[2] = f2bf(f.z); v[3] = f2bf(f.w);
    } else {
        v[0] = v[1] = v[2] = v[3] = 0;
    }
    *reinterpret_cast<u16x4*>(sp + pos) = v;
}

// prep: basis fp32 -> Apack bf16 fragment layout (26624 16B-slots)
__global__ void prep_a(const float* __restrict__ basis,
                       unsigned short* __restrict__ ap) {
    int s = blockIdx.x * 256 + threadIdx.x;   // exactly 104*256 = 26624
    int bm = s / 6656, rem = s % 6656;
    int sip, kb;
    if (rem < 1792)      { sip = rem;        kb = 0;  }
    else if (rem < 3584) { sip = rem - 1792; kb = 7;  }
    else if (rem < 5120) { sip = rem - 3584; kb = 14; }
    else                 { sip = rem - 5120; kb = 20; }
    int ksg = sip >> 7, r = sip & 127;
    int ka = kb + (ksg >> 1);
    int k0 = ka * 16 + (ksg & 1) * 8;
    int m = bm * 128 + r;
    u16x8 v;
#pragma unroll
    for (int j = 0; j < 8; ++j) {
        int k = k0 + j;
        float f = (m < NROWS && k < NTAPS) ? basis[m * NTAPS + k] : 0.0f;
        v[j] = f2bf(f);
    }
    *reinterpret_cast<u16x8*>(ap + (size_t)s * 8) = v;
}

#define A_LOAD(POFF, N) do { _Pragma("unroll") \
    for (int it = 0; it < (N); ++it) { \
        int slot = it * 256 + tid; \
        areg[it] = *reinterpret_cast<const u32x4*>(aBase + (POFF) + slot * 16); \
    } } while (0)

#define A_WRITE(N) do { _Pragma("unroll") \
    for (int it = 0; it < (N); ++it) { \
        int slot = it * 256 + tid; \
        *reinterpret_cast<u32x4*>(aB + (slot & 127) * 240 + (slot >> 7) * 16) = areg[it]; \
    } } while (0)

#define COMPUTE_PHASE(KSB, KSN) do { _Pragma("unroll") \
    for (int i = 0; i < (KSN); ++i) { \
        const int ka = (KSB) + i; \
        const int sc = ka * 32 + (ka >= 10 ? 16 : 0) + (ka >= 20 ? 16 : 0); \
        bf16x8 a0 = *reinterpret_cast<const bf16x8*>(aR0g + i * 32); \
        bf16x8 a1 = *reinterpret_cast<const bf16x8*>(aR0g + 7680 + i * 32); \
        bf16x8 b0 = *reinterpret_cast<const bf16x8*>(sB0 + sc); \
        bf16x8 b1 = *reinterpret_cast<const bf16x8*>(sB0 + 10752 + sc); \
        acc00 = __builtin_amdgcn_mfma_f32_32x32x16_bf16(a0, b0, acc00, 0, 0, 0); \
        acc01 = __builtin_amdgcn_mfma_f32_32x32x16_bf16(a0, b1, acc01, 0, 0, 0); \
        acc10 = __builtin_amdgcn_mfma_f32_32x32x16_bf16(a1, b0, acc10, 0, 0, 0); \
        acc11 = __builtin_amdgcn_mfma_f32_32x32x16_bf16(a1, b1, acc11, 0, 0, 0); \
    } } while (0)

#define STORE_ACC(A, R0, T) do { if ((T) < (long)N_FRAMES) { _Pragma("unroll") \
    for (int r = 0; r < 16; ++r) { \
        int row = (R0) + (r & 3) + 8 * (r >> 2); \
        if (row < NROWS) out[(long)row * N_FRAMES + (T)] = (A)[r]; \
    } } } while (0)

__launch_bounds__(256)
__global__ void stft_gemm(const unsigned short* __restrict__ sigp,
                          const unsigned short* __restrict__ apack,
                          float* __restrict__ out) {
    __shared__ __align__(16) char lds[A_LDS_B + SIG_LDS_B];  // 75776 B -> 2 blocks/CU
    char* aB = lds;
    char* sB = lds + A_LDS_B;
    const int tid = threadIdx.x;
    const int bm = blockIdx.x & 3;          // 128-row block (bm fastest: sig shared)
    const int bt = blockIdx.x >> 2;         // 128-frame block
    const char* aBase = (const char*)apack + (size_t)bm * ABM_STRIDE;

    // issue A phase-0 loads, then sig window gll (latency overlaps)
    u32x4 areg[7];
    A_LOAD(APH0, 7);
    {
        const char* sg = (const char*)sigp + (size_t)bt * 43008;
#pragma unroll
        for (int it = 0; it < 11; ++it) {
            int slot = it * 256 + tid;      // 2816 slots exactly
            gll16(sg + slot * 16, sB + slot * 16);
        }
    }
    A_WRITE(7);
    __syncthreads();

    const int lane = tid & 63;
    const int w = tid >> 6;
    const int wm = w >> 1;                  // 64-row half
    const int wf = w & 1;                   // 64-frame half
    const int l31 = lane & 31;
    const int g = lane >> 5;

    const char* aR0g = aB + (wm * 64 + l31) * 240 + g * 16;
    const char* sB0 = sB + (wf * 64 + l31) * 336 + g * 16;

    f32x16 acc00 = {0,0,0,0,0,0,0,0,0,0,0,0,0,0,0,0};
    f32x16 acc01 = {0,0,0,0,0,0,0,0,0,0,0,0,0,0,0,0};
    f32x16 acc10 = {0,0,0,0,0,0,0,0,0,0,0,0,0,0,0,0};
    f32x16 acc11 = {0,0,0,0,0,0,0,0,0,0,0,0,0,0,0,0};

    A_LOAD(APH1, 7);
    COMPUTE_PHASE(0, 7);
    __syncthreads();
    A_WRITE(7);
    __syncthreads();

    A_LOAD(APH2, 6);
    COMPUTE_PHASE(7, 7);
    __syncthreads();
    A_WRITE(6);
    __syncthreads();

    A_LOAD(APH3, 6);
    COMPUTE_PHASE(14, 6);
    __syncthreads();
    A_WRITE(6);
    __syncthreads();

    COMPUTE_PHASE(20, 6);

    const int rBase = bm * 128 + wm * 64 + 4 * g;
    const long tBase = (long)bt * 128 + wf * 64 + l31;
    STORE_ACC(acc00, rBase, tBase);
    STORE_ACC(acc01, rBase, tBase + 32);
    STORE_ACC(acc10, rBase + 32, tBase);
    STORE_ACC(acc11, rBase + 32, tBase + 32);
}

// ================= TIER 2: R3 fallback (proven 65-73 us) =================
#define MT 13
#define KS 26
#define FPB 128
#define MSPLIT 3
#define NBT ((N_FRAMES + FPB - 1) / FPB)
#define SPAN (127*HOP + 416)
#define SPAN4 (SPAN/4)
#define LDSE 21776

__global__ void stft_prep2(const float* __restrict__ basis,
                           unsigned short* __restrict__ packed) {
    int tid = blockIdx.x * 256 + threadIdx.x;
    if (tid >= MT * KS * 64) return;
    int lane = tid & 63;
    int frag = tid >> 6;
    int ks = frag % KS;
    int mt = frag / KS;
    int row = mt * 32 + (lane & 31);
    int colb = ks * 16 + (lane >> 5) * 8;
    u16x8 v;
#pragma unroll
    for (int i = 0; i < 8; ++i) {
        int col = colb + i;
        float f = (row < NROWS && col < NTAPS) ? basis[row * NTAPS + col] : 0.0f;
        v[i] = f2bf(f);
    }
    *reinterpret_cast<u16x8*>(packed + (size_t)tid * 8) = v;
}

__launch_bounds__(256, 3)
__global__ void stft_mfma2(const float* __restrict__ sig,
                           const unsigned short* __restrict__ packedA,
                           float* __restrict__ out) {
    __shared__ unsigned short sl[LDSE];
    const int tid = threadIdx.x;
    const int bt = blockIdx.x % NBT;
    const int bmm = blockIdx.x / NBT;
    const long sbase = (long)bt * (FPB * HOP) - PAD;
    for (int idx = tid; idx < SPAN4; idx += 256) {
        const int e = idx * 4;
        const long g0 = sbase + e;
        float4 v;
        if (g0 >= 0 && g0 + 4 <= (long)T_SIG) {
            v = *reinterpret_cast<const float4*>(sig + g0);
        } else {
            v.x = (g0 + 0 >= 0 && g0 + 0 < (long)T_SIG) ? sig[g0 + 0] : 0.0f;
            v.y = (g0 + 1 >= 0 && g0 + 1 < (long)T_SIG) ? sig[g0 + 1] : 0.0f;
            v.z = (g0 + 2 >= 0 && g0 + 2 < (long)T_SIG) ? sig[g0 + 2] : 0.0f;
            v.w = (g0 + 3 >= 0 && g0 + 3 < (long)T_SIG) ? sig[g0 + 3] : 0.0f;
        }
        u16x4 s;
        s[0] = f2bf(v.x); s[1] = f2bf(v.y); s[2] = f2bf(v.z); s[3] = f2bf(v.w);
        const int pos = e + 8 * (e / 160);
        *reinterpret_cast<u16x4*>(&sl[pos]) = s;
    }
    __syncthreads();
    const int lane = tid & 63;
    const int w = tid >> 6;
    const int l31 = lane & 31;
    const int g = lane >> 5;
    const int lf = w * 32 + l31;
    const long t = (long)bt * FPB + lf;
    const int mt0 = (bmm == 0) ? 0 : 5 + 4 * (bmm - 1);
    const int mtN = (bmm == 0) ? 5 : 4;
    const unsigned short* bbase = &sl[lf * 168 + g * 8];
    const int rowg = 4 * g;
#pragma unroll 1
    for (int mi = 0; mi < mtN; ++mi) {
        const int mt = mt0 + mi;
        f32x16 acc = {0,0,0,0,0,0,0,0,0,0,0,0,0,0,0,0};
        const unsigned short* pA = packedA + ((size_t)(mt * KS) * 64 + lane) * 8;
#pragma unroll
        for (int ks = 0; ks < KS; ++ks) {
            const bf16x8 a = *reinterpret_cast<const bf16x8*>(pA + (size_t)ks * 512);
            const bf16x8 b = *reinterpret_cast<const bf16x8*>(bbase + ks * 16 + 8 * (ks / 10));
            acc = __builtin_amdgcn_mfma_f32_32x32x16_bf16(a, b, acc, 0, 0, 0);
        }
        if (t < N_FRAMES) {
            const int rb = mt * 32 + rowg;
#pragma unroll
            for (int r = 0; r < 16; ++r) {
                const int row = rb + (r & 3) + 8 * (r >> 2);
                if (row < NROWS) out[(long)row * N_FRAMES + t] = acc[r];
            }
        }
        __syncthreads();
    }
}

// ================= TIER 3: naive =================
__global__ void stft_naive(const float* __restrict__ sig,
                           const float* __restrict__ basis,
                           float* __restrict__ out) {
    long idx = (long)blockIdx.x * 256 + threadIdx.x;
    if (idx >= (long)NROWS * N_FRAMES) return;
    int row = (int)(idx / N_FRAMES);
    int tt = (int)(idx % N_FRAMES);
    long s0 = (long)tt * HOP - PAD;
    float acc = 0.0f;
    for (int n = 0; n < NTAPS; ++n) {
        long s = s0 + n;
        float x = (s >= 0 && s < (long)T_SIG) ? sig[s] : 0.0f;
        acc = fmaf(x, basis[row * NTAPS + n], acc);
    }
    out[idx] = acc;
}

extern "C" void kernel_launch(void* const* d_in, const int* in_sizes, int n_in,
                              void* d_out, int out_size, void* d_ws, size_t ws_size,
                              hipStream_t stream) {
    (void)in_sizes; (void)n_in; (void)out_size;
    const float* sig = (const float*)d_in[0];
    const float* basis = (const float*)d_in[1];
    float* out = (float*)d_out;
    if (ws_size >= NEED1) {
        unsigned short* ap = (unsigned short*)d_ws;
        unsigned short* sp = (unsigned short*)((char*)d_ws + SIG_OFF);
        prep_sig<<<9381, 256, 0, stream>>>(sig, sp);
        prep_a<<<104, 256, 0, stream>>>(basis, ap);
        stft_gemm<<<469 * 4, 256, 0, stream>>>(sp, ap, out);
    } else if (ws_size >= (size_t)MT * KS * 64 * 8 * sizeof(unsigned short)) {
        unsigned short* packed = (unsigned short*)d_ws;
        stft_prep2<<<(MT * KS * 64 + 255) / 256, 256, 0, stream>>>(basis, packed);
        stft_mfma2<<<NBT * MSPLIT, 256, 0, stream>>>(sig, packed, out);
    } else {
        long total = (long)NROWS * N_FRAMES;
        stft_naive<<<(int)((total + 255) / 256), 256, 0, stream>>>(sig, basis, out);
    }
}